// Round 8
// baseline (50.007 us; speedup 1.0000x reference)
//
#include <hip/hip_runtime.h>
#include <hip/hip_bf16.h>

// Forward warp (bilinear splatting), direct per-tile gather-from-window.
//   img  [B=8, C=3, H=180, W=320] f32
//   flow [B=8, 2,  H=180, W=320] f32
//   scale=4 -> out [B, C, 720, 1280] f32
//
// Tile 40x64, margin 6: window 24x30=720 input px per tile (3/thread).
// Derivation (TW=64): hit needs x in [px0-1, px0+TW); x=4(w+fx), |fx|<=6
//   -> w in [wb-6, wb+21]; window starts wb-7, width 30 -> slack 1 each side.
// Rows: h in [hb-6, hb+15]; window starts hb-7, height 24 -> slack 1.
// Pixels with |flow| > 6 are excluded by the EXACT complement predicate and
// splatted with global atomics in a second (vectorized) kernel (~2.5k px for
// this distribution; exact for ANY input).
//
// Load discipline: phase 1 loads FLOW ONLY (batched, independent); phase 2
// computes hit masks; phase 3 batch-loads img only for hit items (~17%);
// phase 4 LDS atomics. Exclusive nontemporal float4 write-out -> no memset.

typedef float f32x4 __attribute__((ext_vector_type(4)));

#define B_ 8
#define C_ 3
#define H_ 180
#define W_ 320
#define HW_ (H_ * W_)
#define SCALE_ 4
#define Ho_ (H_ * SCALE_)            // 720
#define Wo_ (W_ * SCALE_)            // 1280
#define TH_ 40
#define TW_ 64
#define NTY_ (Ho_ / TH_)             // 18
#define NTX_ (Wo_ / TW_)             // 20
#define NTILES_ (B_ * NTY_ * NTX_)   // 2880 (divisible by 8 -> bijective XCD swizzle)
#define NPIX_ (B_ * H_ * W_)         // 460800

#define MARGIN_ 6.0f
#define MARGIN_I_ 6
#define WIN_H_ (TH_ / 4 + 2 * MARGIN_I_ + 2)   // 24
#define WIN_W_ (TW_ / 4 + 2 * MARGIN_I_ + 2)   // 30
#define WIN_ITEMS_ (WIN_H_ * WIN_W_)           // 720 (<= 3*256)
#define ITEMS_PT_ 3
#define PLANE_STRIDE_ 2564                     // 2560+4: channels -> distinct banks, 16B-aligned
#define LDS_FLOATS_ (C_ * PLANE_STRIDE_)       // 7692 floats = 30768 B -> 5 blocks/CU

__global__ __launch_bounds__(256) void warp_tile_kernel(const float* __restrict__ img,
                                                        const float* __restrict__ flow,
                                                        float* __restrict__ out) {
    __shared__ __align__(16) float acc[LDS_FLOATS_];

    // XCD-chunked swizzle (2880 % 8 == 0 -> bijective).
    int tile = (int)(blockIdx.x & 7) * (NTILES_ / 8) + (int)(blockIdx.x >> 3);
    const int tx = tile % NTX_;
    const int tt = tile / NTX_;
    const int ty = tt % NTY_;
    const int b  = tt / NTY_;
    const int px0 = tx * TW_;
    const int py0 = ty * TH_;

    for (int j = threadIdx.x; j < LDS_FLOATS_ / 4; j += 256)
        *reinterpret_cast<f32x4*>(&acc[j * 4]) = (f32x4)(0.f);
    __syncthreads();

    const float* __restrict__ fxp  = flow + (size_t)(b * 2 + 0) * HW_;
    const float* __restrict__ fyp  = flow + (size_t)(b * 2 + 1) * HW_;
    const float* __restrict__ imgb = img + (size_t)b * C_ * HW_;

    const int hb = py0 >> 2;
    const int wb = px0 >> 2;

    // ---- phase 1: batched independent FLOW loads ----
    float fxv[ITEMS_PT_], fyv[ITEMS_PT_];
    int hwv[ITEMS_PT_];
    int hv[ITEMS_PT_], wv[ITEMS_PT_];
    bool av[ITEMS_PT_];
    #pragma unroll
    for (int k = 0; k < ITEMS_PT_; ++k) {
        int i = (int)threadIdx.x + k * 256;
        int r = i / WIN_W_;
        int c = i - r * WIN_W_;
        int h = hb - (MARGIN_I_ + 1) + r;
        int w = wb - (MARGIN_I_ + 1) + c;
        bool act = (i < WIN_ITEMS_) &&
                   ((unsigned)h < (unsigned)H_) && ((unsigned)w < (unsigned)W_);
        int hw = act ? (h * W_ + w) : 0;
        av[k] = act; hv[k] = h; wv[k] = w; hwv[k] = hw;
        fxv[k] = fxp[hw];
        fyv[k] = fyp[hw];
    }

    // ---- phase 2: geometry + hit masks (no memory ops) ----
    int ix0v[ITEMS_PT_], iy0v[ITEMS_PT_];
    float axv[ITEMS_PT_], ayv[ITEMS_PT_];
    bool hitv[ITEMS_PT_];
    #pragma unroll
    for (int k = 0; k < ITEMS_PT_; ++k) {
        float fx = fxv[k], fy = fyv[k];
        // Must be the EXACT complement of outlier_kernel's predicate.
        bool inl = av[k] && fabsf(fx) <= MARGIN_ && fabsf(fy) <= MARGIN_;
        float x = ((float)wv[k] + fx) * (float)SCALE_;
        float y = ((float)hv[k] + fy) * (float)SCALE_;
        float x0f = floorf(x), y0f = floorf(y);
        int ix0 = (int)x0f - px0;   // tile-local
        int iy0 = (int)y0f - py0;
        bool cx = ((unsigned)ix0 < (unsigned)TW_) | ((unsigned)(ix0 + 1) < (unsigned)TW_);
        bool cy = ((unsigned)iy0 < (unsigned)TH_) | ((unsigned)(iy0 + 1) < (unsigned)TH_);
        hitv[k] = inl && cx && cy;
        ix0v[k] = ix0; iy0v[k] = iy0;
        axv[k] = x - x0f; ayv[k] = y - y0f;
    }

    // ---- phase 3: batched img loads ONLY for hit items ----
    float v0v[ITEMS_PT_], v1v[ITEMS_PT_], v2v[ITEMS_PT_];
    #pragma unroll
    for (int k = 0; k < ITEMS_PT_; ++k) {
        if (hitv[k]) {
            int hw = hwv[k];
            v0v[k] = imgb[hw];
            v1v[k] = imgb[HW_ + hw];
            v2v[k] = imgb[2 * HW_ + hw];
        }
    }

    // ---- phase 4: LDS accumulate ----
    #pragma unroll
    for (int k = 0; k < ITEMS_PT_; ++k) {
        if (!hitv[k]) continue;
        int ix0 = ix0v[k], iy0 = iy0v[k];
        float ax = axv[k], ay = ayv[k];
        float wxs[2] = {1.0f - ax, ax};
        float wys[2] = {1.0f - ay, ay};
        bool cxs[2] = {(unsigned)ix0 < (unsigned)TW_, (unsigned)(ix0 + 1) < (unsigned)TW_};
        bool cys[2] = {(unsigned)iy0 < (unsigned)TH_, (unsigned)(iy0 + 1) < (unsigned)TH_};
        #pragma unroll
        for (int ky = 0; ky < 2; ++ky) {
            if (!cys[ky]) continue;
            #pragma unroll
            for (int kx = 0; kx < 2; ++kx) {
                if (!cxs[kx]) continue;
                float wt = wxs[kx] * wys[ky];
                int la = (iy0 + ky) * TW_ + (ix0 + kx);
                atomicAdd(&acc[la], v0v[k] * wt);
                atomicAdd(&acc[la + PLANE_STRIDE_], v1v[k] * wt);
                atomicAdd(&acc[la + 2 * PLANE_STRIDE_], v2v[k] * wt);
            }
        }
    }
    __syncthreads();

    // ---- phase 5: exclusive coalesced nontemporal float4 write-out ----
    const size_t outb = (size_t)b * C_ * Ho_ * Wo_;
    const int F4_PER_PLANE = TH_ * TW_ / 4;        // 640
    const int F4_PER_ROW   = TW_ / 4;              // 16
    for (int j = threadIdx.x; j < C_ * F4_PER_PLANE; j += 256) {
        int ch  = j / F4_PER_PLANE;
        int rem = j - ch * F4_PER_PLANE;
        int yy  = rem / F4_PER_ROW;
        int xx4 = rem - yy * F4_PER_ROW;
        f32x4 v = *reinterpret_cast<const f32x4*>(&acc[ch * PLANE_STRIDE_ + yy * TW_ + xx4 * 4]);
        __builtin_nontemporal_store(v,
            reinterpret_cast<f32x4*>(
                &out[outb + (size_t)ch * Ho_ * Wo_ + (size_t)(py0 + yy) * Wo_ + px0 + xx4 * 4]));
    }
}

// Pixels with |flow| > MARGIN_: exact global-atomic splat (AFTER tile writes).
// Vectorized: 4 px/thread via f32x4 flow loads; fast path = all inliers.
__global__ __launch_bounds__(256) void outlier_kernel(const float* __restrict__ img,
                                                      const float* __restrict__ flow,
                                                      float* __restrict__ out) {
    int q = blockIdx.x * 256 + threadIdx.x;   // grid exactly NPIX_/4/256 = 450
    int idx = q * 4;
    int b = idx / HW_;                         // HW_ % 4 == 0 -> same b for all 4
    int hw = idx - b * HW_;
    f32x4 fx4 = *reinterpret_cast<const f32x4*>(&flow[(size_t)(b * 2 + 0) * HW_ + hw]);
    f32x4 fy4 = *reinterpret_cast<const f32x4*>(&flow[(size_t)(b * 2 + 1) * HW_ + hw]);

    bool ol[4];
    bool any = false;
    #pragma unroll
    for (int j = 0; j < 4; ++j) {
        ol[j] = !(fabsf(fx4[j]) <= MARGIN_ && fabsf(fy4[j]) <= MARGIN_);
        any |= ol[j];
    }
    if (!any) return;

    const float* imgb = img + (size_t)b * C_ * HW_;
    const size_t out_b = (size_t)b * C_ * Ho_ * Wo_;
    const size_t chs = (size_t)Ho_ * Wo_;
    #pragma unroll
    for (int j = 0; j < 4; ++j) {
        if (!ol[j]) continue;
        int hwj = hw + j;
        int h = hwj / W_;
        int w = hwj - h * W_;
        float x = ((float)w + fx4[j]) * (float)SCALE_;
        float y = ((float)h + fy4[j]) * (float)SCALE_;
        float x0f = floorf(x), y0f = floorf(y);
        float ax = x - x0f, ay = y - y0f;
        int ix0 = (int)x0f, iy0 = (int)y0f;
        float v0 = imgb[hwj];
        float v1 = imgb[HW_ + hwj];
        float v2 = imgb[2 * HW_ + hwj];
        float wxs[2] = {1.0f - ax, ax};
        float wys[2] = {1.0f - ay, ay};
        #pragma unroll
        for (int ky = 0; ky < 2; ++ky) {
            int yi = iy0 + ky;
            if ((unsigned)yi >= (unsigned)Ho_) continue;
            #pragma unroll
            for (int kx = 0; kx < 2; ++kx) {
                int xi = ix0 + kx;
                if ((unsigned)xi >= (unsigned)Wo_) continue;
                float wt = wxs[kx] * wys[ky];
                size_t base = out_b + (size_t)yi * Wo_ + (size_t)xi;
                atomicAdd(&out[base + 0 * chs], v0 * wt);
                atomicAdd(&out[base + 1 * chs], v1 * wt);
                atomicAdd(&out[base + 2 * chs], v2 * wt);
            }
        }
    }
}

// ---------------- fallback: naive global-atomic splat (scale != 4) ----------------
__global__ __launch_bounds__(256) void splat_naive(const float* __restrict__ img,
                                                   const float* __restrict__ flow,
                                                   const int* __restrict__ scale_p,
                                                   float* __restrict__ out) {
    int idx = blockIdx.x * blockDim.x + threadIdx.x;
    if (idx >= NPIX_) return;
    const int s = *scale_p;
    const int Ho = H_ * s, Wo = W_ * s;
    int w = idx % W_;
    int t = idx / W_;
    int h = t % H_;
    int b = t / H_;
    const int hw = h * W_ + w;
    float fx = flow[((b * 2 + 0) * H_) * W_ + hw];
    float fy = flow[((b * 2 + 1) * H_) * W_ + hw];
    float x = ((float)w + fx) * (float)s;
    float y = ((float)h + fy) * (float)s;
    float x0f = floorf(x), y0f = floorf(y);
    float ax = x - x0f, ay = y - y0f;
    int ix0 = (int)x0f, iy0 = (int)y0f;
    const size_t img_b = (size_t)b * C_ * HW_;
    float v0 = img[img_b + 0 * (size_t)HW_ + hw];
    float v1 = img[img_b + 1 * (size_t)HW_ + hw];
    float v2 = img[img_b + 2 * (size_t)HW_ + hw];
    const size_t out_b = (size_t)b * C_ * Ho * Wo;
    const size_t out_chs = (size_t)Ho * Wo;
    float wxs[2] = {1.0f - ax, ax};
    float wys[2] = {1.0f - ay, ay};
    #pragma unroll
    for (int ky = 0; ky < 2; ++ky) {
        int yi = iy0 + ky;
        if (yi < 0 || yi > Ho - 1) continue;
        #pragma unroll
        for (int kx = 0; kx < 2; ++kx) {
            int xi = ix0 + kx;
            if (xi < 0 || xi > Wo - 1) continue;
            float wt = wxs[kx] * wys[ky];
            size_t base = out_b + (size_t)yi * Wo + (size_t)xi;
            atomicAdd(&out[base + 0 * out_chs], v0 * wt);
            atomicAdd(&out[base + 1 * out_chs], v1 * wt);
            atomicAdd(&out[base + 2 * out_chs], v2 * wt);
        }
    }
}

extern "C" void kernel_launch(void* const* d_in, const int* in_sizes, int n_in,
                              void* d_out, int out_size, void* d_ws, size_t ws_size,
                              hipStream_t stream) {
    const float* img   = (const float*)d_in[0];
    const float* flow  = (const float*)d_in[1];
    const int*   scale = (const int*)d_in[2];
    float* out = (float*)d_out;

    const bool scale4 = (out_size == B_ * C_ * Ho_ * Wo_);

    if (scale4) {
        warp_tile_kernel<<<NTILES_, 256, 0, stream>>>(img, flow, out);
        outlier_kernel<<<NPIX_ / 4 / 256, 256, 0, stream>>>(img, flow, out);
    } else {
        (void)hipMemsetAsync(out, 0, (size_t)out_size * sizeof(float), stream);
        splat_naive<<<(NPIX_ + 255) / 256, 256, 0, stream>>>(img, flow, scale, out);
    }
}